// Round 10
// baseline (170.116 us; speedup 1.0000x reference)
//
#include <hip/hip_runtime.h>
#include <stdint.h>

#define N_BATCH 32
#define B_OBJ   36
#define D_DIM   2048
#define Q_DIM   1024

typedef __bf16 bf16x8 __attribute__((ext_vector_type(8)));
typedef float  f32x4  __attribute__((ext_vector_type(4)));

__device__ __forceinline__ uint16_t f2bf(float f) {
    uint32_t u = __builtin_bit_cast(uint32_t, f);
    uint32_t r = (u + 0x7FFFu + ((u >> 16) & 1u)) >> 16;   // RNE
    return (uint16_t)r;
}

__device__ __forceinline__ void gld_lds16(const void* g, void* l) {
    __builtin_amdgcn_global_load_lds(
        (const __attribute__((address_space(1))) uint32_t*)g,
        (__attribute__((address_space(3))) uint32_t*)l, 16, 0, 0);
}

// ---- transpose + fp32->bf16, 64x64 tiles, vectorized ----
__global__ __launch_bounds__(256) void transpose_all(
    const float* __restrict__ W1, const float* __restrict__ W2,
    const float* __restrict__ W3,
    uint16_t* __restrict__ W1t, uint16_t* __restrict__ W2t,
    uint16_t* __restrict__ W3t) {
    __shared__ float tile[64][65];
    int gy = blockIdx.y;
    const float* W; uint16_t* Wt; int K, k0;
    if (gy < 32)      { W = W1; Wt = W1t; K = 2048; k0 = gy * 64; }
    else if (gy < 64) { W = W2; Wt = W2t; K = 2048; k0 = (gy - 32) * 64; }
    else              { W = W3; Wt = W3t; K = 1024; k0 = (gy - 64) * 64; }
    int n0 = blockIdx.x * 64;
    int t = threadIdx.x;
    {
        int r = t >> 4, c = (t & 15) * 4;
#pragma unroll
        for (int p = 0; p < 4; ++p)
            *(float4*)&tile[r + p * 16][c] =
                *(const float4*)&W[(size_t)(k0 + r + p * 16) * 2048 + n0 + c];
    }
    __syncthreads();
    {
        int n = t >> 2, kb = (t & 3) * 16;
#pragma unroll
        for (int g4 = 0; g4 < 4; ++g4) {
            int k = kb + g4 * 4;
            ushort4 o;
            o.x = f2bf(tile[k][n]);     o.y = f2bf(tile[k + 1][n]);
            o.z = f2bf(tile[k + 2][n]); o.w = f2bf(tile[k + 3][n]);
            *(ushort4*)&Wt[(size_t)(n0 + n) * K + k0 + k] = o;
        }
    }
}

// ---- qe GEMM: qpart[z] = q @ W3 over K-chunk z (M=32, N=2048, split-K=4) ----
__global__ __launch_bounds__(256) void qk_gemm(
    const float* __restrict__ q,
    const uint16_t* __restrict__ W3t,
    float* __restrict__ qpart) {
    __shared__ __align__(16) uint16_t As[32][32];
    __shared__ __align__(16) uint16_t Bs[128][32];
    int t = threadIdx.x, lane = t & 63, wave = t >> 6;
    int l15 = lane & 15, quad = lane >> 4;
    int n0 = blockIdx.x * 128;
    int kbase = blockIdx.y * 256;
    f32x4 acc[2][2] = {};
    int ar = t >> 3, ac = (t & 7) * 4;
    int br = t >> 2, bk = (t & 3) * 8;

    for (int k0 = 0; k0 < 256; k0 += 32) {
        __syncthreads();
        float4 av = *(const float4*)&q[(size_t)ar * Q_DIM + kbase + k0 + ac];
        ushort4 a4;
        a4.x = f2bf(av.x); a4.y = f2bf(av.y); a4.z = f2bf(av.z); a4.w = f2bf(av.w);
        *(ushort4*)&As[ar][ac] = a4;
        *(uint4*)&Bs[br][bk]      = *(const uint4*)&W3t[(size_t)(n0 + br) * Q_DIM + kbase + k0 + bk];
        *(uint4*)&Bs[br + 64][bk] = *(const uint4*)&W3t[(size_t)(n0 + br + 64) * Q_DIM + kbase + k0 + bk];
        __syncthreads();
        bf16x8 af[2], bfr[2];
        af[0]  = *(const bf16x8*)&As[l15][quad * 8];
        af[1]  = *(const bf16x8*)&As[16 + l15][quad * 8];
        bfr[0] = *(const bf16x8*)&Bs[wave * 32 + l15][quad * 8];
        bfr[1] = *(const bf16x8*)&Bs[wave * 32 + 16 + l15][quad * 8];
#pragma unroll
        for (int i = 0; i < 2; ++i)
#pragma unroll
            for (int j = 0; j < 2; ++j)
                acc[i][j] = __builtin_amdgcn_mfma_f32_16x16x32_bf16(af[i], bfr[j], acc[i][j], 0, 0, 0);
    }
    float* dst = qpart + (size_t)blockIdx.y * 32 * D_DIM;
#pragma unroll
    for (int i = 0; i < 2; ++i)
#pragma unroll
        for (int j = 0; j < 2; ++j) {
            int n = n0 + wave * 32 + j * 16 + l15;
#pragma unroll
            for (int r = 0; r < 4; ++r)
                dst[(size_t)(i * 16 + quad * 4 + r) * D_DIM + n] = acc[i][j][r];
        }
}

// ---- fused: qe = relu(sum_z qpart + b3) (in regs); u[n,i,d] = bf16(v*qe) ----
// grid (4, N_BATCH), 128 threads; block owns a 512-float d-chunk of batch nb.
__global__ __launch_bounds__(128) void qe_make_u(
    const float* __restrict__ qpart, const float* __restrict__ b3,
    const float* __restrict__ v, uint16_t* __restrict__ u) {
    int nb = blockIdx.y;
    int d4 = blockIdx.x * 128 + threadIdx.x;          // float4 index in row (512/row)
    const float4* p = (const float4*)qpart;
    size_t base = (size_t)nb * 512 + d4;
    float4 s0 = p[base], s1 = p[16384 + base], s2 = p[32768 + base], s3 = p[49152 + base];
    float4 b = ((const float4*)b3)[d4];
    float4 qe;
    qe.x = fmaxf(s0.x + s1.x + s2.x + s3.x + b.x, 0.f);
    qe.y = fmaxf(s0.y + s1.y + s2.y + s3.y + b.y, 0.f);
    qe.z = fmaxf(s0.z + s1.z + s2.z + s3.z + b.z, 0.f);
    qe.w = fmaxf(s0.w + s1.w + s2.w + s3.w + b.w, 0.f);
    const float4* v4 = (const float4*)v;
    ushort4* u4 = (ushort4*)u;
    size_t rb = (size_t)nb * B_OBJ * 512 + d4;
#pragma unroll 4
    for (int i = 0; i < B_OBJ; ++i) {
        float4 vv = v4[rb + (size_t)i * 512];
        ushort4 o;
        o.x = f2bf(vv.x * qe.x);
        o.y = f2bf(vv.y * qe.y);
        o.z = f2bf(vv.z * qe.z);
        o.w = f2bf(vv.w * qe.w);
        u4[rb + (size_t)i * 512] = o;
    }
}

// ---- pair-batched GEMM: tile M=72 real (2 batches x 36) x N=128, K=2048, BK=128 ----
// Ring-of-3 LDS buffers, ONE barrier per K-step (T3 minimal): at step k, issue
// STAGE(k+2) into buf[(k+2)%3] (no readers/writers), compute buf[k%3], then
// vmcnt(L) (stage k+1 retired; k+2 stays in flight) + s_barrier. Stage flight
// = 2 compute phases; 16 barriers per gemm (was 31); A-junk staging removed.
// Buffer = A 72x128 bf16 row-major (18 KB, granule-XOR swizzled) + B [4q][128][32]
// (32 KB, slot-swizzled) = 51200 B; x3 = 153600 B dynamic LDS (<= 160 KB).
// 50 regions of 1KB/step: waves 0-1 issue 7, waves 2-7 issue 6.
// 512 threads = 8 waves tiled 2(M: batch-in-pair) x 4(N). Wave reads A rows
// wr*36 + (i*16+l15); positions 36-47 of each half read in-buffer garbage
// (finite bf16) and are discarded by the epilogue row mapping.
// mode 0: pairsum epilogue -> x (bf16). mode 1: relu(+bias) -> out (f32).
__global__ __launch_bounds__(512) void gemm_batch(
    const uint16_t* __restrict__ A,    // 1152 x 2048 bf16 (32 batches x 36 rows)
    const uint16_t* __restrict__ Bt,   // 2048 x 2048 bf16 (n-major)
    const float* __restrict__ bias,
    void* __restrict__ Cv,
    int mode) {
    extern __shared__ __align__(16) uint16_t smem[];   // 3 x 25600 u16
    float* yt = (float*)smem;                          // epilogue: [96][132] f32

    int t = threadIdx.x, lane = t & 63, wave = t >> 6;
    int l15 = lane & 15, quad = lane >> 4;
    int wr = wave >> 2, wc = wave & 3;         // wave: batch wr, cols wc*32
    int nbp = blockIdx.y;                      // batch pair: 2*nbp, 2*nbp+1
    int n0 = blockIdx.x * 128;
    const uint16_t* Ab = A + (size_t)nbp * 72 * D_DIM;   // exactly 72 real rows

    // 50 regions of 1KB, region r = wave + 8c (waves 0-1: c<7, waves 2-7: c<6):
    //  r<18: A region: 4 rows x 128 u16 (full BK row-major). Lane -> row
    //        r*4+(lane>>4), stored granule (lane&15) holds global granule
    //        (lane&15)^(row&7)  [XOR swizzle, involution].
    //  r>=18: B region rb=r-18: h=rb>>3 (K-quarter), g=rb&7 (rowgroup).
    //        Lane -> row g*16+(lane>>2), slot (lane&3) holds global slot
    //        (lane&3)^((lane>>2)&3).
    const uint16_t* gp[7];
    int loff[7];
    int wslot = (lane & 3) ^ ((lane >> 2) & 3);
#pragma unroll
    for (int c = 0; c < 7; ++c) {
        int r = wave + 8 * c;
        int rr = (r < 50) ? r : 0;
        if (rr < 18) {
            int row = rr * 4 + (lane >> 4);
            gp[c] = Ab + (size_t)row * D_DIM + ((lane & 15) ^ (row & 7)) * 8;
            loff[c] = rr * 512;
        } else {
            int rb = rr - 18, h = rb >> 3, g = rb & 7;
            int brow = g * 16 + (lane >> 2);
            gp[c] = Bt + (size_t)(n0 + brow) * D_DIM + h * 32 + wslot * 8;
            loff[c] = 9216 + h * 4096 + g * 512;
        }
    }

    f32x4 acc[3][2] = {};
    // read-side swizzles:
    int axor  = (4 * wr + l15) & 7;        // A: (row&7) for rows wr*36+i*16+l15
    int rslot = quad ^ (l15 & 3);          // B: same as staged involution

#define STAGE(kk, bi)                                            \
    {                                                            \
        _Pragma("unroll")                                        \
        for (int c = 0; c < 7; ++c)                              \
            if (wave + 8 * c < 50)                               \
                gld_lds16(gp[c] + (kk), smem + (bi) * 25600 + loff[c]); \
    }
#define WAIT_L()                                                      \
    {                                                                 \
        if (wave < 2) asm volatile("s_waitcnt vmcnt(7)" ::: "memory");\
        else          asm volatile("s_waitcnt vmcnt(6)" ::: "memory");\
    }

    // prologue: stage 0 and 1; wait for stage0 only (stage1 in flight)
    STAGE(0, 0);
    STAGE(128, 1);
    WAIT_L();
    __builtin_amdgcn_s_barrier();

    int cur = 0;
    for (int k = 0; k < 16; ++k) {
        if (k < 14) {
            int stb = (cur >= 1) ? cur - 1 : 2;    // (cur+2)%3 — untouched buffer
            STAGE((k + 2) * 128, stb);
        }
        const uint16_t* As = smem + cur * 25600;
        const uint16_t* Bs = As + 9216;
#pragma unroll
        for (int s = 0; s < 4; ++s) {
            bf16x8 af[3], bfr[2];
#pragma unroll
            for (int i = 0; i < 3; ++i)
                af[i] = *(const bf16x8*)(As + (wr * 36 + i * 16 + l15) * 128 +
                                         ((4 * s + quad) ^ axor) * 8);
#pragma unroll
            for (int j = 0; j < 2; ++j)
                bfr[j] = *(const bf16x8*)(Bs + s * 4096 +
                                          (wc * 32 + j * 16 + l15) * 32 + rslot * 8);
#pragma unroll
            for (int i = 0; i < 3; ++i)
#pragma unroll
                for (int j = 0; j < 2; ++j)
                    acc[i][j] = __builtin_amdgcn_mfma_f32_16x16x32_bf16(af[i], bfr[j], acc[i][j], 0, 0, 0);
        }
        if (k == 15) break;
        if (k < 14) {
            WAIT_L();                              // stage k+1 retired; k+2 flying
        } else {                                   // k == 14: drain stage 15
            asm volatile("s_waitcnt vmcnt(0)" ::: "memory");
        }
        __builtin_amdgcn_s_barrier();              // single barrier per step
        cur = (cur < 2) ? cur + 1 : 0;
    }
#undef STAGE
#undef WAIT_L

    if (mode == 0) {
        uint16_t* X = (uint16_t*)Cv;
        __syncthreads();   // all waves done with K-loop before smem reuse as yt
#pragma unroll
        for (int i = 0; i < 3; ++i)
#pragma unroll
            for (int j = 0; j < 2; ++j)
#pragma unroll
                for (int r = 0; r < 4; ++r)
                    yt[(wr * 48 + i * 16 + quad * 4 + r) * 132 + wc * 32 + j * 16 + l15] = acc[i][j][r];
        __syncthreads();
        int col = t & 127, sub = t >> 7;           // sub: 0..3
        int b = sub >> 1, half = sub & 1;          // batch-in-pair, row-half
        float bv = bias[n0 + col];
        float z[36];
#pragma unroll
        for (int j = 0; j < 36; ++j) z[j] = yt[(b * 48 + j) * 132 + col];
#pragma unroll
        for (int ii = 0; ii < 18; ++ii) {
            int i = half * 18 + ii;
            float zi = z[i] + bv;
            float s = 0.f;
#pragma unroll
            for (int j = 0; j < 36; ++j) s += fmaxf(zi + z[j], 0.f);
            X[(size_t)((nbp * 2 + b) * B_OBJ + i) * D_DIM + n0 + col] = f2bf(s);
        }
    } else {
        float* O = (float*)Cv;
#pragma unroll
        for (int i = 0; i < 3; ++i)
#pragma unroll
            for (int r = 0; r < 4; ++r) {
                int obj = i * 16 + quad * 4 + r;   // row within this wave's batch
                if (obj < B_OBJ) {
#pragma unroll
                    for (int j = 0; j < 2; ++j) {
                        int cc = n0 + wc * 32 + j * 16 + l15;
                        O[(size_t)((nbp * 2 + wr) * B_OBJ + obj) * D_DIM + cc] =
                            fmaxf(acc[i][j][r] + bias[cc], 0.f);
                    }
                }
            }
    }
}

extern "C" void kernel_launch(void* const* d_in, const int* in_sizes, int n_in,
                              void* d_out, int out_size, void* d_ws, size_t ws_size,
                              hipStream_t stream) {
    const float* v  = (const float*)d_in[0];
    const float* q  = (const float*)d_in[1];
    const float* W1 = (const float*)d_in[2];
    const float* b1 = (const float*)d_in[3];
    const float* W2 = (const float*)d_in[4];
    const float* b2 = (const float*)d_in[5];
    const float* W3 = (const float*)d_in[6];
    const float* b3 = (const float*)d_in[7];
    float* out = (float*)d_out;

    char* ws = (char*)d_ws;
    uint16_t* W1t   = (uint16_t*)(ws + 0);           // 8 MiB
    uint16_t* W2t   = (uint16_t*)(ws + 8388608);     // 8 MiB
    uint16_t* W3t   = (uint16_t*)(ws + 16777216);    // 4 MiB, dead after qk_gemm
    uint16_t* u     = (uint16_t*)(ws + 16777216);    // 4.5 MiB (overlays dead W3t)
    float*    qpart = (float*)   (ws + 21495808);    // 1 MiB
    uint16_t* x     = (uint16_t*)(ws + 22806528);    // 4.5 MiB (ends 27525120)

    // allow 153600 B of dynamic LDS for the ring-3 pipeline (capture-safe)
    static bool attr_done = false;
    if (!attr_done) {
        (void)hipFuncSetAttribute((const void*)gemm_batch,
                                  hipFuncAttributeMaxDynamicSharedMemorySize, 153600);
        attr_done = true;
    }

    transpose_all<<<dim3(32, 80), 256, 0, stream>>>(W1, W2, W3, W1t, W2t, W3t);

    qk_gemm<<<dim3(16, 4), 256, 0, stream>>>(q, W3t, qpart);

    qe_make_u<<<dim3(4, N_BATCH), 128, 0, stream>>>(qpart, b3, v, u);

    // GEMM1 + fused pairsum -> x (bf16); 16 batch pairs
    gemm_batch<<<dim3(16, 16), 512, 153600, stream>>>(u, W1t, b1, x, 0);

    // GEMM2 + bias + relu -> out (f32)
    gemm_batch<<<dim3(16, 16), 512, 153600, stream>>>(x, W2t, b2, out, 1);
}